// Round 7
// baseline (1181.943 us; speedup 1.0000x reference)
//
#include <hip/hip_runtime.h>
#include <stdint.h>

// d_out (f32) layout: seed [64][3][256] @0, x3 [64][128][256] @49152,
// fps x [64][3][512] @2146304.  x3 region doubles as x1 staging.
#define X3_OFF 49152
#define FPS_OFF 2146304

// ws (f32) layout: T1 @0, T1s @8192, T3 @16384, T3s @24576 (each [128][64]),
// featT [512][64] @32768.  Total 65536 floats = 256 KB.

// ---------------------------------------------------------------------------
// k_prep: featT[c][b] = feat[b][c]
// ---------------------------------------------------------------------------
__global__ void k_prep(const float* __restrict__ feat, float* __restrict__ ws) {
    int g = blockIdx.x * 256 + threadIdx.x;   // 32768
    int c = g >> 6, b = g & 63;
    ws[32768 + c * 64 + b] = feat[b * 512 + c];
}

// ---------------------------------------------------------------------------
// k_tterms: T[o][b] = sum_c W[o][128+c] * feat[b][c] for the 4 concat weights
// ---------------------------------------------------------------------------
__global__ void k_tterms(const float* __restrict__ w1, const float* __restrict__ ws1,
                         const float* __restrict__ w3, const float* __restrict__ ws3,
                         float* __restrict__ ws) {
    int g = blockIdx.x * 256 + threadIdx.x;   // 32768
    int which = g >> 13;
    int o = (g >> 6) & 127;
    int b = g & 63;
    const float* W = (which == 0) ? w1 : (which == 1) ? ws1
                     : (which == 2) ? w3 : ws3;
    const float* ft = ws + 32768;
    float acc = 0.f;
    for (int c = 0; c < 512; ++c)
        acc = fmaf(W[o * 640 + 128 + c], ft[c * 64 + b], acc);
    ws[which * 8192 + o * 64 + b] = acc;
}

// ---------------------------------------------------------------------------
// k_deconv (v2): x1[b][o][k] = sum_c feat[b][c]*ps_w[c][o][k] + ps_b[o]
// y-blocks = 2 (32 batches each) -> psw HBM traffic 128 MB instead of 256 MB.
// ---------------------------------------------------------------------------
__global__ void k_deconv(const float* __restrict__ psw,
                         const float* __restrict__ psb,
                         const float* __restrict__ ws,
                         float* __restrict__ stage) {
    int n = blockIdx.x * 256 + threadIdx.x;   // 32768 = o*256+k
    int b0 = blockIdx.y * 32;
    const float* featT = ws + 32768;
    float acc[32];
    float bias = psb[n >> 8];
#pragma unroll
    for (int j = 0; j < 32; ++j) acc[j] = bias;
    for (int c = 0; c < 512; ++c) {
        float pw = psw[c * 32768 + n];
#pragma unroll
        for (int j = 0; j < 32; ++j)
            acc[j] = fmaf(pw, featT[c * 64 + b0 + j], acc[j]);
    }
#pragma unroll
    for (int j = 0; j < 32; ++j)
        stage[(b0 + j) * 32768 + n] = acc[j];
}

// ---------------------------------------------------------------------------
// gemm8: acc[r] += sum_i S[i][lane] * Wg[(o0+r)*ld + i]  (o0 wave-uniform)
// ---------------------------------------------------------------------------
__device__ __forceinline__ void gemm8(const float* __restrict__ Wg, int ld, int o0,
                                      const float* S, int K, float acc[8], int lane) {
#pragma unroll 4
    for (int i = 0; i < K; ++i) {
        float x = S[i * 64 + lane];
#pragma unroll
        for (int r = 0; r < 8; ++r)
            acc[r] = fmaf(x, Wg[(o0 + r) * ld + i], acc[r]);
    }
}

// ---------------------------------------------------------------------------
// k_fused: per (b, 64-wide k-tile): x1 -> m1 -> m2 -> m3 -> m4/seed.
// ---------------------------------------------------------------------------
struct FusedW {
    const float *m1_w1, *m1_b1, *m1_w2, *m1_b2, *m1_ws, *m1_bs;
    const float *m2_w1, *m2_b1, *m2_w2, *m2_b2, *m2_ws, *m2_bs;
    const float *m3_w1, *m3_b1, *m3_w2, *m3_b2, *m3_ws, *m3_bs;
    const float *m4_w1, *m4_b1, *m4_w2, *m4_b2;
};

__global__ void __launch_bounds__(512)
k_fused(FusedW P, const float* __restrict__ ws, float* __restrict__ fout) {
    int b  = blockIdx.x >> 2;
    int k0 = (blockIdx.x & 3) * 64;
    int lane = threadIdx.x & 63;
    int wave = __builtin_amdgcn_readfirstlane(threadIdx.x >> 6);

    const float* T1  = ws;
    const float* T1s = ws + 8192;
    const float* T3  = ws + 16384;
    const float* T3s = ws + 24576;
    float* stage = fout + X3_OFF + b * 32768;

    __shared__ float Xs[8192];
    __shared__ float Hs[8192];

#pragma unroll
    for (int s = 0; s < 16; ++s) {
        int e = threadIdx.x + s * 512;
        int o = e >> 6, kk = e & 63;
        Xs[e] = stage[o * 256 + k0 + kk];
    }
    __syncthreads();

    float yreg[2][8];

    // ================= m1 =================
#pragma unroll
    for (int half = 0; half < 2; ++half) {
        int o0 = wave * 16 + half * 8;
        float acc[8];
#pragma unroll
        for (int r = 0; r < 8; ++r) acc[r] = T1[(o0 + r) * 64 + b] + P.m1_b1[o0 + r];
        gemm8(P.m1_w1, 640, o0, Xs, 128, acc, lane);
#pragma unroll
        for (int r = 0; r < 8; ++r) Hs[(o0 + r) * 64 + lane] = fmaxf(acc[r], 0.f);
    }
    __syncthreads();
#pragma unroll
    for (int half = 0; half < 2; ++half) {
        int o0 = wave * 16 + half * 8;
        float acc[8];
#pragma unroll
        for (int r = 0; r < 8; ++r)
            acc[r] = T1s[(o0 + r) * 64 + b] + P.m1_b2[o0 + r] + P.m1_bs[o0 + r];
        gemm8(P.m1_w2, 128, o0, Hs, 128, acc, lane);
        gemm8(P.m1_ws, 640, o0, Xs, 128, acc, lane);
#pragma unroll
        for (int r = 0; r < 8; ++r) yreg[half][r] = acc[r];
    }
    __syncthreads();
#pragma unroll
    for (int half = 0; half < 2; ++half) {
        int o0 = wave * 16 + half * 8;
#pragma unroll
        for (int r = 0; r < 8; ++r) Xs[(o0 + r) * 64 + lane] = yreg[half][r];
    }
    __syncthreads();

    // ================= m2 =================
    {
        int o0 = wave * 8;
        float acc[8];
#pragma unroll
        for (int r = 0; r < 8; ++r) acc[r] = P.m2_b1[o0 + r];
        gemm8(P.m2_w1, 128, o0, Xs, 128, acc, lane);
#pragma unroll
        for (int r = 0; r < 8; ++r) Hs[(o0 + r) * 64 + lane] = fmaxf(acc[r], 0.f);
    }
    __syncthreads();
#pragma unroll
    for (int half = 0; half < 2; ++half) {
        int o0 = wave * 16 + half * 8;
        float acc[8];
#pragma unroll
        for (int r = 0; r < 8; ++r) acc[r] = P.m2_b2[o0 + r] + P.m2_bs[o0 + r];
        gemm8(P.m2_w2, 64, o0, Hs, 64, acc, lane);
        gemm8(P.m2_ws, 128, o0, Xs, 128, acc, lane);
#pragma unroll
        for (int r = 0; r < 8; ++r) yreg[half][r] = acc[r];
    }
    __syncthreads();
#pragma unroll
    for (int half = 0; half < 2; ++half) {
        int o0 = wave * 16 + half * 8;
#pragma unroll
        for (int r = 0; r < 8; ++r) Xs[(o0 + r) * 64 + lane] = yreg[half][r];
    }
    __syncthreads();

    // ================= m3 =================
#pragma unroll
    for (int half = 0; half < 2; ++half) {
        int o0 = wave * 16 + half * 8;
        float acc[8];
#pragma unroll
        for (int r = 0; r < 8; ++r) acc[r] = T3[(o0 + r) * 64 + b] + P.m3_b1[o0 + r];
        gemm8(P.m3_w1, 640, o0, Xs, 128, acc, lane);
#pragma unroll
        for (int r = 0; r < 8; ++r) Hs[(o0 + r) * 64 + lane] = fmaxf(acc[r], 0.f);
    }
    __syncthreads();
#pragma unroll
    for (int half = 0; half < 2; ++half) {
        int o0 = wave * 16 + half * 8;
        float acc[8];
#pragma unroll
        for (int r = 0; r < 8; ++r)
            acc[r] = T3s[(o0 + r) * 64 + b] + P.m3_b2[o0 + r] + P.m3_bs[o0 + r];
        gemm8(P.m3_w2, 128, o0, Hs, 128, acc, lane);
        gemm8(P.m3_ws, 640, o0, Xs, 128, acc, lane);
#pragma unroll
        for (int r = 0; r < 8; ++r) yreg[half][r] = acc[r];
    }
    __syncthreads();
#pragma unroll
    for (int half = 0; half < 2; ++half) {
        int o0 = wave * 16 + half * 8;
#pragma unroll
        for (int r = 0; r < 8; ++r) {
            Xs[(o0 + r) * 64 + lane] = yreg[half][r];
            stage[(o0 + r) * 256 + k0 + lane] = yreg[half][r];
        }
    }
    __syncthreads();

    // ================= m4 / seed =================
    {
        int o0 = wave * 8;
        float acc[8];
#pragma unroll
        for (int r = 0; r < 8; ++r) acc[r] = P.m4_b1[o0 + r];
        gemm8(P.m4_w1, 128, o0, Xs, 128, acc, lane);
#pragma unroll
        for (int r = 0; r < 8; ++r) Hs[(o0 + r) * 64 + lane] = fmaxf(acc[r], 0.f);
    }
    __syncthreads();
    if (wave < 3) {
        int d = wave;
        float s = P.m4_b2[d];
        for (int j = 0; j < 64; ++j)
            s = fmaf(Hs[j * 64 + lane], P.m4_w2[d * 64 + j], s);
        fout[b * 768 + d * 256 + k0 + lane] = s;
    }
}

// ---------------------------------------------------------------------------
// k_fps (v3): TWO batches per block (independent serial chains interleave ->
// latency hiding). 256 threads; 17 pts/thread/batch in registers. Centroid
// fetched from global (L2-warm, block-uniform address). LDS only holds
// candidates + selected-index history (4.4 KB). Reduction payload = u64
// (dist_bits<<13 | (8191-gidx)): max => max dist, tie -> min index.
// ---------------------------------------------------------------------------
__global__ void __launch_bounds__(256, 1)
k_fps(const float* __restrict__ seed, const float* __restrict__ partial,
      float* __restrict__ outx) {
    int bA = blockIdx.x * 2;
    int bB = bA + 1;
    int tid = threadIdx.x;        // 0..255
    int lane = tid & 63;
    int wv = tid >> 6;            // 0..3

    __shared__ unsigned long long cand[2][2][4];   // [pingpong][batch][wave]
    __shared__ int fars[2][512];

    float pxA[17], pyA[17], pzA[17], dA[17];
    float pxB[17], pyB[17], pzB[17], dB[17];

    // ---- stage: s==0 -> seed pts (idx 0..255), s>=1 -> partial ----
    {
        pxA[0] = seed[bA * 768 + tid];
        pyA[0] = seed[bA * 768 + 256 + tid];
        pzA[0] = seed[bA * 768 + 512 + tid];
        pxB[0] = seed[bB * 768 + tid];
        pyB[0] = seed[bB * 768 + 256 + tid];
        pzB[0] = seed[bB * 768 + 512 + tid];
        dA[0] = 1e10f; dB[0] = 1e10f;
    }
#pragma unroll
    for (int s = 1; s < 17; ++s) {
        int e = s * 256 + tid - 256;             // 0..4095
        int baseA = (bA * 4096 + e) * 3;
        int baseB = (bB * 4096 + e) * 3;
        pxA[s] = partial[baseA]; pyA[s] = partial[baseA + 1]; pzA[s] = partial[baseA + 2];
        pxB[s] = partial[baseB]; pyB[s] = partial[baseB + 1]; pzB[s] = partial[baseB + 2];
        dA[s] = 1e10f; dB[s] = 1e10f;
    }
    if (tid == 0) { fars[0][0] = 0; fars[1][0] = 0; }

    float cxA = seed[bA * 768], cyA = seed[bA * 768 + 256], czA = seed[bA * 768 + 512];
    float cxB = seed[bB * 768], cyB = seed[bB * 768 + 256], czB = seed[bB * 768 + 512];

    for (int t = 0; t < 511; ++t) {
        // ---- batch A local argmax ----
        float bvA = -1.0f; int bgA = 0;
#pragma unroll
        for (int s = 0; s < 17; ++s) {
            float dx = pxA[s] - cxA, dy = pyA[s] - cyA, dz = pzA[s] - czA;
            float d = __fadd_rn(__fadd_rn(__fmul_rn(dx, dx), __fmul_rn(dy, dy)),
                                __fmul_rn(dz, dz));
            dA[s] = fminf(dA[s], d);
            if (dA[s] > bvA) { bvA = dA[s]; bgA = s * 256 + tid; }
        }
        // ---- batch B local argmax ----
        float bvB = -1.0f; int bgB = 0;
#pragma unroll
        for (int s = 0; s < 17; ++s) {
            float dx = pxB[s] - cxB, dy = pyB[s] - cyB, dz = pzB[s] - czB;
            float d = __fadd_rn(__fadd_rn(__fmul_rn(dx, dx), __fmul_rn(dy, dy)),
                                __fmul_rn(dz, dz));
            dB[s] = fminf(dB[s], d);
            if (dB[s] > bvB) { bvB = dB[s]; bgB = s * 256 + tid; }
        }
        unsigned long long UA =
            (((unsigned long long)__float_as_uint(bvA)) << 13) |
            (unsigned long long)(8191 - bgA);
        unsigned long long UB =
            (((unsigned long long)__float_as_uint(bvB)) << 13) |
            (unsigned long long)(8191 - bgB);

        // two independent 6-stage butterflies (interleaved by scheduler)
#pragma unroll
        for (int off = 32; off >= 1; off >>= 1) {
            unsigned long long oA = (unsigned long long)__shfl_xor((long long)UA, off, 64);
            unsigned long long oB = (unsigned long long)__shfl_xor((long long)UB, off, 64);
            if (oA > UA) UA = oA;
            if (oB > UB) UB = oB;
        }
        if (lane == 0) {
            cand[t & 1][0][wv] = UA;
            cand[t & 1][1][wv] = UB;
        }
        __syncthreads();
        unsigned long long A0 = cand[t & 1][0][0], A1 = cand[t & 1][0][1];
        unsigned long long A2 = cand[t & 1][0][2], A3 = cand[t & 1][0][3];
        unsigned long long B0 = cand[t & 1][1][0], B1 = cand[t & 1][1][1];
        unsigned long long B2 = cand[t & 1][1][2], B3 = cand[t & 1][1][3];
        if (A1 > A0) A0 = A1;
        if (A3 > A2) A2 = A3;
        if (A2 > A0) A0 = A2;
        if (B1 > B0) B0 = B1;
        if (B3 > B2) B2 = B3;
        if (B2 > B0) B0 = B2;
        int biA = 8191 - (int)(A0 & 8191ull);
        int biB = 8191 - (int)(B0 & 8191ull);
        if (tid == 0) { fars[0][t + 1] = biA; fars[1][t + 1] = biB; }

        // centroid fetch (block-uniform branch; L2-warm)
        if (biA < 256) {
            int base = bA * 768 + biA;
            cxA = seed[base]; cyA = seed[base + 256]; czA = seed[base + 512];
        } else {
            int base = (bA * 4096 + biA - 256) * 3;
            cxA = partial[base]; cyA = partial[base + 1]; czA = partial[base + 2];
        }
        if (biB < 256) {
            int base = bB * 768 + biB;
            cxB = seed[base]; cyB = seed[base + 256]; czB = seed[base + 512];
        } else {
            int base = (bB * 4096 + biB - 256) * 3;
            cxB = partial[base]; cyB = partial[base + 1]; czB = partial[base + 2];
        }
    }
    __syncthreads();

    // ---- gather outputs: x [b][3][512] ----
#pragma unroll
    for (int j = 0; j < 2; ++j) {
        int n = tid + j * 256;
        {
            int idx = fars[0][n];
            float x, y, z;
            if (idx < 256) {
                int base = bA * 768 + idx;
                x = seed[base]; y = seed[base + 256]; z = seed[base + 512];
            } else {
                int base = (bA * 4096 + idx - 256) * 3;
                x = partial[base]; y = partial[base + 1]; z = partial[base + 2];
            }
            int ob = bA * 1536 + n;
            outx[ob] = x; outx[ob + 512] = y; outx[ob + 1024] = z;
        }
        {
            int idx = fars[1][n];
            float x, y, z;
            if (idx < 256) {
                int base = bB * 768 + idx;
                x = seed[base]; y = seed[base + 256]; z = seed[base + 512];
            } else {
                int base = (bB * 4096 + idx - 256) * 3;
                x = partial[base]; y = partial[base + 1]; z = partial[base + 2];
            }
            int ob = bB * 1536 + n;
            outx[ob] = x; outx[ob + 512] = y; outx[ob + 1024] = z;
        }
    }
}

// ---------------------------------------------------------------------------
extern "C" void kernel_launch(void* const* d_in, const int* in_sizes, int n_in,
                              void* d_out, int out_size, void* d_ws, size_t ws_size,
                              hipStream_t stream) {
    (void)in_sizes; (void)n_in; (void)out_size; (void)ws_size;
    const float* feat    = (const float*)d_in[0];
    const float* partial = (const float*)d_in[3];
    const float* psw     = (const float*)d_in[4];
    const float* psb     = (const float*)d_in[5];

    FusedW P;
    P.m1_w1 = (const float*)d_in[6];  P.m1_b1 = (const float*)d_in[7];
    P.m1_w2 = (const float*)d_in[8];  P.m1_b2 = (const float*)d_in[9];
    P.m1_ws = (const float*)d_in[10]; P.m1_bs = (const float*)d_in[11];
    P.m2_w1 = (const float*)d_in[12]; P.m2_b1 = (const float*)d_in[13];
    P.m2_w2 = (const float*)d_in[14]; P.m2_b2 = (const float*)d_in[15];
    P.m2_ws = (const float*)d_in[16]; P.m2_bs = (const float*)d_in[17];
    P.m3_w1 = (const float*)d_in[18]; P.m3_b1 = (const float*)d_in[19];
    P.m3_w2 = (const float*)d_in[20]; P.m3_b2 = (const float*)d_in[21];
    P.m3_ws = (const float*)d_in[22]; P.m3_bs = (const float*)d_in[23];
    P.m4_w1 = (const float*)d_in[24]; P.m4_b1 = (const float*)d_in[25];
    P.m4_w2 = (const float*)d_in[26]; P.m4_b2 = (const float*)d_in[27];

    float* W = (float*)d_ws;
    float* out = (float*)d_out;

    k_prep<<<dim3(128), dim3(256), 0, stream>>>(feat, W);
    k_tterms<<<dim3(128), dim3(256), 0, stream>>>(P.m1_w1, P.m1_ws, P.m3_w1, P.m3_ws, W);
    k_deconv<<<dim3(128, 2), dim3(256), 0, stream>>>(psw, psb, W, out + X3_OFF);
    k_fused<<<dim3(256), dim3(512), 0, stream>>>(P, W, out);
    k_fps<<<dim3(32), dim3(256), 0, stream>>>(out, partial, out + FPS_OFF);
}

// Round 8
// 729.852 us; speedup vs baseline: 1.6194x; 1.6194x over previous
//
#include <hip/hip_runtime.h>
#include <stdint.h>

// d_out (f32) layout: seed [64][3][256] @0, x3 [64][128][256] @49152,
// fps x [64][3][512] @2146304.  x3 region doubles as x1 staging.
#define X3_OFF 49152
#define FPS_OFF 2146304

// ws (f32) layout: T1 @0, T1s @8192, T3 @16384, T3s @24576 (each [128][64]),
// featT [512][64] @32768.  Total 65536 floats = 256 KB.

// ---------------------------------------------------------------------------
// k_prep: featT[c][b] = feat[b][c]
// ---------------------------------------------------------------------------
__global__ void k_prep(const float* __restrict__ feat, float* __restrict__ ws) {
    int g = blockIdx.x * 256 + threadIdx.x;   // 32768
    int c = g >> 6, b = g & 63;
    ws[32768 + c * 64 + b] = feat[b * 512 + c];
}

// ---------------------------------------------------------------------------
// k_tterms: T[o][b] = sum_c W[o][128+c] * feat[b][c] for the 4 concat weights
// ---------------------------------------------------------------------------
__global__ void k_tterms(const float* __restrict__ w1, const float* __restrict__ ws1,
                         const float* __restrict__ w3, const float* __restrict__ ws3,
                         float* __restrict__ ws) {
    int g = blockIdx.x * 256 + threadIdx.x;   // 32768
    int which = g >> 13;
    int o = (g >> 6) & 127;
    int b = g & 63;
    const float* W = (which == 0) ? w1 : (which == 1) ? ws1
                     : (which == 2) ? w3 : ws3;
    const float* ft = ws + 32768;
    float acc = 0.f;
    for (int c = 0; c < 512; ++c)
        acc = fmaf(W[o * 640 + 128 + c], ft[c * 64 + b], acc);
    ws[which * 8192 + o * 64 + b] = acc;
}

// ---------------------------------------------------------------------------
// k_deconv (R6-proven): x1[b][o][k] = sum_c feat[b][c]*ps_w[c][o][k] + ps_b[o]
// acc[16], y-blocks=4.  // acc[32] variant spilled (R7: no launch_bounds)
// ---------------------------------------------------------------------------
__global__ void k_deconv(const float* __restrict__ psw,
                         const float* __restrict__ psb,
                         const float* __restrict__ ws,
                         float* __restrict__ stage) {
    int n = blockIdx.x * 256 + threadIdx.x;   // 32768 = o*256+k
    int b0 = blockIdx.y * 16;
    const float* featT = ws + 32768;
    float acc[16];
    float bias = psb[n >> 8];
#pragma unroll
    for (int j = 0; j < 16; ++j) acc[j] = bias;
    for (int c = 0; c < 512; ++c) {
        float pw = psw[c * 32768 + n];
#pragma unroll
        for (int j = 0; j < 16; ++j)
            acc[j] = fmaf(pw, featT[c * 64 + b0 + j], acc[j]);
    }
#pragma unroll
    for (int j = 0; j < 16; ++j)
        stage[(b0 + j) * 32768 + n] = acc[j];
}

// ---------------------------------------------------------------------------
// gemm8: acc[r] += sum_i S[i][lane] * Wg[(o0+r)*ld + i]  (o0 wave-uniform)
// ---------------------------------------------------------------------------
__device__ __forceinline__ void gemm8(const float* __restrict__ Wg, int ld, int o0,
                                      const float* S, int K, float acc[8], int lane) {
#pragma unroll 4
    for (int i = 0; i < K; ++i) {
        float x = S[i * 64 + lane];
#pragma unroll
        for (int r = 0; r < 8; ++r)
            acc[r] = fmaf(x, Wg[(o0 + r) * ld + i], acc[r]);
    }
}

// ---------------------------------------------------------------------------
// k_fused: per (b, 64-wide k-tile): x1 -> m1 -> m2 -> m3 -> m4/seed.
// ---------------------------------------------------------------------------
struct FusedW {
    const float *m1_w1, *m1_b1, *m1_w2, *m1_b2, *m1_ws, *m1_bs;
    const float *m2_w1, *m2_b1, *m2_w2, *m2_b2, *m2_ws, *m2_bs;
    const float *m3_w1, *m3_b1, *m3_w2, *m3_b2, *m3_ws, *m3_bs;
    const float *m4_w1, *m4_b1, *m4_w2, *m4_b2;
};

__global__ void __launch_bounds__(512)
k_fused(FusedW P, const float* __restrict__ ws, float* __restrict__ fout) {
    int b  = blockIdx.x >> 2;
    int k0 = (blockIdx.x & 3) * 64;
    int lane = threadIdx.x & 63;
    int wave = __builtin_amdgcn_readfirstlane(threadIdx.x >> 6);

    const float* T1  = ws;
    const float* T1s = ws + 8192;
    const float* T3  = ws + 16384;
    const float* T3s = ws + 24576;
    float* stage = fout + X3_OFF + b * 32768;

    __shared__ float Xs[8192];
    __shared__ float Hs[8192];

#pragma unroll
    for (int s = 0; s < 16; ++s) {
        int e = threadIdx.x + s * 512;
        int o = e >> 6, kk = e & 63;
        Xs[e] = stage[o * 256 + k0 + kk];
    }
    __syncthreads();

    float yreg[2][8];

    // ================= m1 =================
#pragma unroll
    for (int half = 0; half < 2; ++half) {
        int o0 = wave * 16 + half * 8;
        float acc[8];
#pragma unroll
        for (int r = 0; r < 8; ++r) acc[r] = T1[(o0 + r) * 64 + b] + P.m1_b1[o0 + r];
        gemm8(P.m1_w1, 640, o0, Xs, 128, acc, lane);
#pragma unroll
        for (int r = 0; r < 8; ++r) Hs[(o0 + r) * 64 + lane] = fmaxf(acc[r], 0.f);
    }
    __syncthreads();
#pragma unroll
    for (int half = 0; half < 2; ++half) {
        int o0 = wave * 16 + half * 8;
        float acc[8];
#pragma unroll
        for (int r = 0; r < 8; ++r)
            acc[r] = T1s[(o0 + r) * 64 + b] + P.m1_b2[o0 + r] + P.m1_bs[o0 + r];
        gemm8(P.m1_w2, 128, o0, Hs, 128, acc, lane);
        gemm8(P.m1_ws, 640, o0, Xs, 128, acc, lane);
#pragma unroll
        for (int r = 0; r < 8; ++r) yreg[half][r] = acc[r];
    }
    __syncthreads();
#pragma unroll
    for (int half = 0; half < 2; ++half) {
        int o0 = wave * 16 + half * 8;
#pragma unroll
        for (int r = 0; r < 8; ++r) Xs[(o0 + r) * 64 + lane] = yreg[half][r];
    }
    __syncthreads();

    // ================= m2 =================
    {
        int o0 = wave * 8;
        float acc[8];
#pragma unroll
        for (int r = 0; r < 8; ++r) acc[r] = P.m2_b1[o0 + r];
        gemm8(P.m2_w1, 128, o0, Xs, 128, acc, lane);
#pragma unroll
        for (int r = 0; r < 8; ++r) Hs[(o0 + r) * 64 + lane] = fmaxf(acc[r], 0.f);
    }
    __syncthreads();
#pragma unroll
    for (int half = 0; half < 2; ++half) {
        int o0 = wave * 16 + half * 8;
        float acc[8];
#pragma unroll
        for (int r = 0; r < 8; ++r) acc[r] = P.m2_b2[o0 + r] + P.m2_bs[o0 + r];
        gemm8(P.m2_w2, 64, o0, Hs, 64, acc, lane);
        gemm8(P.m2_ws, 128, o0, Xs, 128, acc, lane);
#pragma unroll
        for (int r = 0; r < 8; ++r) yreg[half][r] = acc[r];
    }
    __syncthreads();
#pragma unroll
    for (int half = 0; half < 2; ++half) {
        int o0 = wave * 16 + half * 8;
#pragma unroll
        for (int r = 0; r < 8; ++r) Xs[(o0 + r) * 64 + lane] = yreg[half][r];
    }
    __syncthreads();

    // ================= m3 =================
#pragma unroll
    for (int half = 0; half < 2; ++half) {
        int o0 = wave * 16 + half * 8;
        float acc[8];
#pragma unroll
        for (int r = 0; r < 8; ++r) acc[r] = T3[(o0 + r) * 64 + b] + P.m3_b1[o0 + r];
        gemm8(P.m3_w1, 640, o0, Xs, 128, acc, lane);
#pragma unroll
        for (int r = 0; r < 8; ++r) Hs[(o0 + r) * 64 + lane] = fmaxf(acc[r], 0.f);
    }
    __syncthreads();
#pragma unroll
    for (int half = 0; half < 2; ++half) {
        int o0 = wave * 16 + half * 8;
        float acc[8];
#pragma unroll
        for (int r = 0; r < 8; ++r)
            acc[r] = T3s[(o0 + r) * 64 + b] + P.m3_b2[o0 + r] + P.m3_bs[o0 + r];
        gemm8(P.m3_w2, 128, o0, Hs, 128, acc, lane);
        gemm8(P.m3_ws, 640, o0, Xs, 128, acc, lane);
#pragma unroll
        for (int r = 0; r < 8; ++r) yreg[half][r] = acc[r];
    }
    __syncthreads();
#pragma unroll
    for (int half = 0; half < 2; ++half) {
        int o0 = wave * 16 + half * 8;
#pragma unroll
        for (int r = 0; r < 8; ++r) {
            Xs[(o0 + r) * 64 + lane] = yreg[half][r];
            stage[(o0 + r) * 256 + k0 + lane] = yreg[half][r];
        }
    }
    __syncthreads();

    // ================= m4 / seed =================
    {
        int o0 = wave * 8;
        float acc[8];
#pragma unroll
        for (int r = 0; r < 8; ++r) acc[r] = P.m4_b1[o0 + r];
        gemm8(P.m4_w1, 128, o0, Xs, 128, acc, lane);
#pragma unroll
        for (int r = 0; r < 8; ++r) Hs[(o0 + r) * 64 + lane] = fmaxf(acc[r], 0.f);
    }
    __syncthreads();
    if (wave < 3) {
        int d = wave;
        float s = P.m4_b2[d];
        for (int j = 0; j < 64; ++j)
            s = fmaf(Hs[j * 64 + lane], P.m4_w2[d * 64 + j], s);
        fout[b * 768 + d * 256 + k0 + lane] = s;
    }
}

// ---------------------------------------------------------------------------
// DPP wave-64 reductions (canonical GCN pattern: row_shr 1/2/4/8 +
// row_bcast15 (rows 1,3) + row_bcast31 (rows 2,3)); result in lane 63.
// Identity-old makes masked/invalid lanes no-ops.
// ---------------------------------------------------------------------------
__device__ __forceinline__ unsigned wave_max_u32_l63(unsigned v) {
    unsigned t;
    t = (unsigned)__builtin_amdgcn_update_dpp(0, (int)v, 0x111, 0xf, 0xf, false); v = t > v ? t : v;
    t = (unsigned)__builtin_amdgcn_update_dpp(0, (int)v, 0x112, 0xf, 0xf, false); v = t > v ? t : v;
    t = (unsigned)__builtin_amdgcn_update_dpp(0, (int)v, 0x114, 0xf, 0xf, false); v = t > v ? t : v;
    t = (unsigned)__builtin_amdgcn_update_dpp(0, (int)v, 0x118, 0xf, 0xf, false); v = t > v ? t : v;
    t = (unsigned)__builtin_amdgcn_update_dpp(0, (int)v, 0x142, 0xa, 0xf, false); v = t > v ? t : v;
    t = (unsigned)__builtin_amdgcn_update_dpp(0, (int)v, 0x143, 0xc, 0xf, false); v = t > v ? t : v;
    return v;
}
__device__ __forceinline__ unsigned wave_min_u32_l63(unsigned v) {
    unsigned t;
    t = (unsigned)__builtin_amdgcn_update_dpp(-1, (int)v, 0x111, 0xf, 0xf, false); v = t < v ? t : v;
    t = (unsigned)__builtin_amdgcn_update_dpp(-1, (int)v, 0x112, 0xf, 0xf, false); v = t < v ? t : v;
    t = (unsigned)__builtin_amdgcn_update_dpp(-1, (int)v, 0x114, 0xf, 0xf, false); v = t < v ? t : v;
    t = (unsigned)__builtin_amdgcn_update_dpp(-1, (int)v, 0x118, 0xf, 0xf, false); v = t < v ? t : v;
    t = (unsigned)__builtin_amdgcn_update_dpp(-1, (int)v, 0x142, 0xa, 0xf, false); v = t < v ? t : v;
    t = (unsigned)__builtin_amdgcn_update_dpp(-1, (int)v, 0x143, 0xc, 0xf, false); v = t < v ? t : v;
    return v;
}

// ---------------------------------------------------------------------------
// k_fps (v4 = v2 + DPP reduce): one block of 256 threads per batch;
// 4352 pts = 256*17 in registers (dist update) AND mirrored in LDS
// (centroid broadcast + output gather). Wave reduce: phase-1 DPP max on
// dist bits (u32-monotone, dist>=0) -> readlane63; phase-2 DPP min on
// tie-candidate index -> readlane63. Exact jnp.argmax tie semantics.
// ---------------------------------------------------------------------------
__global__ void __launch_bounds__(256)
k_fps(const float* __restrict__ seed, const float* __restrict__ partial,
      float* __restrict__ outx) {
    int b = blockIdx.x;
    int tid = threadIdx.x;        // 0..255
    int lane = tid & 63;
    int wv = tid >> 6;            // 0..3

    __shared__ float pts[4352 * 3];          // [idx][3]
    __shared__ unsigned long long cand[2][4];
    __shared__ int fars[512];

    // stage seed [b][3][256] -> pts[idx<256]
    pts[tid * 3 + 0] = seed[b * 768 + tid];
    pts[tid * 3 + 1] = seed[b * 768 + 256 + tid];
    pts[tid * 3 + 2] = seed[b * 768 + 512 + tid];
    // stage partial [b][4096][3] -> pts[256..4351]  (linear 12288 dwords)
#pragma unroll
    for (int j = 0; j < 48; ++j) {
        int e = tid + j * 256;
        pts[768 + e] = partial[b * 12288 + e];
    }
    if (tid == 0) fars[0] = 0;
    __syncthreads();

    float px[17], py[17], pz[17], dist[17];
#pragma unroll
    for (int s = 0; s < 17; ++s) {
        int g = s * 256 + tid;
        px[s] = pts[g * 3 + 0];
        py[s] = pts[g * 3 + 1];
        pz[s] = pts[g * 3 + 2];
        dist[s] = 1e10f;
    }
    float cx = pts[0], cy = pts[1], cz = pts[2];

    for (int t = 0; t < 511; ++t) {
        // update running min-dist; local best (max dist, min gidx first-hit)
        float bv = -1.0f; int bg = 0;
#pragma unroll
        for (int s = 0; s < 17; ++s) {
            float dx = px[s] - cx, dy = py[s] - cy, dz = pz[s] - cz;
            float d = __fadd_rn(__fadd_rn(__fmul_rn(dx, dx), __fmul_rn(dy, dy)),
                                __fmul_rn(dz, dz));
            dist[s] = fminf(dist[s], d);
            if (dist[s] > bv) { bv = dist[s]; bg = s * 256 + tid; }
        }
        // phase 1: wave max of dist bits (dist >= 0 so u32 order == f32 order)
        unsigned mv = wave_max_u32_l63(__float_as_uint(bv));
        unsigned maxbits = (unsigned)__builtin_amdgcn_readlane((int)mv, 63);
        // phase 2: wave min of candidate global index among exact-max ties
        unsigned cg = (__float_as_uint(bv) == maxbits) ? (unsigned)bg : 0xFFFFFFFFu;
        unsigned mgv = wave_min_u32_l63(cg);
        unsigned big = (unsigned)__builtin_amdgcn_readlane((int)mgv, 63);

        if (lane == 0)
            cand[t & 1][wv] = (((unsigned long long)maxbits) << 32) |
                              (unsigned long long)(8191u - big);
        __syncthreads();
        unsigned long long U0 = cand[t & 1][0];
        unsigned long long U1 = cand[t & 1][1];
        unsigned long long U2 = cand[t & 1][2];
        unsigned long long U3 = cand[t & 1][3];
        if (U1 > U0) U0 = U1;
        if (U3 > U2) U2 = U3;
        if (U2 > U0) U0 = U2;
        int bi = 8191 - (int)(U0 & 8191ull);
        cx = pts[bi * 3 + 0]; cy = pts[bi * 3 + 1]; cz = pts[bi * 3 + 2];
        if (tid == 0) fars[t + 1] = bi;
    }
    __syncthreads();

    // gather outputs: x [b][3][512]
#pragma unroll
    for (int j = 0; j < 2; ++j) {
        int n = tid + j * 256;
        int idx = fars[n];
        int ob = b * 1536 + n;
        outx[ob]        = pts[idx * 3 + 0];
        outx[ob + 512]  = pts[idx * 3 + 1];
        outx[ob + 1024] = pts[idx * 3 + 2];
    }
}

// ---------------------------------------------------------------------------
extern "C" void kernel_launch(void* const* d_in, const int* in_sizes, int n_in,
                              void* d_out, int out_size, void* d_ws, size_t ws_size,
                              hipStream_t stream) {
    (void)in_sizes; (void)n_in; (void)out_size; (void)ws_size;
    const float* feat    = (const float*)d_in[0];
    const float* partial = (const float*)d_in[3];
    const float* psw     = (const float*)d_in[4];
    const float* psb     = (const float*)d_in[5];

    FusedW P;
    P.m1_w1 = (const float*)d_in[6];  P.m1_b1 = (const float*)d_in[7];
    P.m1_w2 = (const float*)d_in[8];  P.m1_b2 = (const float*)d_in[9];
    P.m1_ws = (const float*)d_in[10]; P.m1_bs = (const float*)d_in[11];
    P.m2_w1 = (const float*)d_in[12]; P.m2_b1 = (const float*)d_in[13];
    P.m2_w2 = (const float*)d_in[14]; P.m2_b2 = (const float*)d_in[15];
    P.m2_ws = (const float*)d_in[16]; P.m2_bs = (const float*)d_in[17];
    P.m3_w1 = (const float*)d_in[18]; P.m3_b1 = (const float*)d_in[19];
    P.m3_w2 = (const float*)d_in[20]; P.m3_b2 = (const float*)d_in[21];
    P.m3_ws = (const float*)d_in[22]; P.m3_bs = (const float*)d_in[23];
    P.m4_w1 = (const float*)d_in[24]; P.m4_b1 = (const float*)d_in[25];
    P.m4_w2 = (const float*)d_in[26]; P.m4_b2 = (const float*)d_in[27];

    float* W = (float*)d_ws;
    float* out = (float*)d_out;

    k_prep<<<dim3(128), dim3(256), 0, stream>>>(feat, W);
    k_tterms<<<dim3(128), dim3(256), 0, stream>>>(P.m1_w1, P.m1_ws, P.m3_w1, P.m3_ws, W);
    k_deconv<<<dim3(128, 4), dim3(256), 0, stream>>>(psw, psb, W, out + X3_OFF);
    k_fused<<<dim3(256), dim3(512), 0, stream>>>(P, W, out);
    k_fps<<<dim3(64), dim3(256), 0, stream>>>(out, partial, out + FPS_OFF);
}